// Round 7
// baseline (210.561 us; speedup 1.0000x reference)
//
#include <hip/hip_runtime.h>

// DotProductAttention: SQ=SK=2048, B=2, NP=32, HN=64, causal, f32 in, f32 out.
// Q/K/V [s][b][n][h] -> flat s*4096 + hd*64 + h, hd = b*32+n.  Out: same.
//
// R7: attn = verified R5 pipeline (BK=32 double-buffered global_load_lds,
// vmcnt(2) prefetch-across-barrier, unnormalized exp2 softmax, per-wave P
// LDS round-trip) + R6's 1-VALU P pack.  prep = new register-transpose
// kernel: no LDS, no __syncthreads, coalesced reads AND writes (the 4 lanes
// covering one 64B output line write in the same instruction).

typedef __attribute__((ext_vector_type(8))) short frag8;   // 8 x bf16
typedef __attribute__((ext_vector_type(4))) float f32x4;

#define SQ_    2048
#define NH_    64
#define HN_    64
#define ROWS_  4096
#define P_P    40      // P LDS pitch (80B rows, 16B aligned)
#define SC2    (0.125f * 1.44269504088896340736f)   // 1/sqrt(64)*log2(e)

__device__ __forceinline__ unsigned short f2bf(float f) {   // RNE
    unsigned u = __float_as_uint(f);
    u += 0x7fffu + ((u >> 16) & 1u);
    return (unsigned short)(u >> 16);
}

__device__ __forceinline__ float fexp2(float x) {
#if __has_builtin(__builtin_amdgcn_exp2f)
    return __builtin_amdgcn_exp2f(x);
#else
    return exp2f(x);
#endif
}

__device__ __forceinline__ frag8 pack8s(const float* __restrict__ p, float s) {
    float4 a = *(const float4*)p;
    float4 b = *(const float4*)(p + 4);
    frag8 r;
    r[0] = (short)f2bf(a.x * s); r[1] = (short)f2bf(a.y * s);
    r[2] = (short)f2bf(a.z * s); r[3] = (short)f2bf(a.w * s);
    r[4] = (short)f2bf(b.x * s); r[5] = (short)f2bf(b.y * s);
    r[6] = (short)f2bf(b.z * s); r[7] = (short)f2bf(b.w * s);
    return r;
}

// async global->LDS, 16B/lane; LDS dst wave-uniform (HW adds lane*16)
__device__ __forceinline__ void gll(const void* g, void* l) {
    __builtin_amdgcn_global_load_lds(
        (const __attribute__((address_space(1))) unsigned int*)(uintptr_t)g,
        (__attribute__((address_space(3))) unsigned int*)(unsigned int)(uintptr_t)l,
        16, 0, 0);
}

// ---------------- prep (register transpose, no LDS / no sync) ----------------
// Kh[hd][s][chunk c of 8 d @ (c+s)%8]                               (16 MiB)
// Vblk[hd][tb][d][chunk u of 8 t @ (u+rv(d))%4], rv(d)=(d+(d>>1))&3 (16 MiB)
// grid: 64 heads x 8 slabs of 256 seq rows; 256 threads.
__global__ void __launch_bounds__(256)
prep_kv2(const float* __restrict__ K, const float* __restrict__ V,
         unsigned short* __restrict__ Kh, unsigned short* __restrict__ Vblk)
{
    const int tid = threadIdx.x;
    const int hd  = blockIdx.x & 63;
    const int s0  = (blockIdx.x >> 6) << 8;     // 256-row slab

    // ---- K: 4 threads/row cast+swizzle, 4 passes ----
    {
        const int c2 = tid & 3;
        const int r0 = tid >> 2;                // 0..63
#pragma unroll
        for (int p = 0; p < 4; ++p) {
            const int s = s0 + p * 64 + r0;
            const float* kp = K + (size_t)s * ROWS_ + hd * HN_ + c2 * 16;
            frag8 A  = pack8s(kp, 1.0f);
            frag8 Bf = pack8s(kp + 8, 1.0f);
            unsigned short* kr = Kh + (size_t)hd * (SQ_ * HN_) + (size_t)s * HN_;
            *(frag8*)(kr + ((2 * c2 + s) & 7) * 8)     = A;
            *(frag8*)(kr + ((2 * c2 + 1 + s) & 7) * 8) = Bf;
        }
    }

    // ---- V: per-thread 8t x 8d register transpose ----
    {
        const int dblk = tid & 7;               // d chunk (8 d)
        const int tblk = tid >> 3;              // 0..31 (8-key group)
        const int tg   = s0 + tblk * 8;
        float m[8][8];
#pragma unroll
        for (int i = 0; i < 8; ++i) {
            const float* vp = V + (size_t)(tg + i) * ROWS_ + hd * HN_ + dblk * 8;
            float4 a = *(const float4*)vp;
            float4 b = *(const float4*)(vp + 4);
            m[i][0] = a.x; m[i][1] = a.y; m[i][2] = a.z; m[i][3] = a.w;
            m[i][4] = b.x; m[i][5] = b.y; m[i][6] = b.z; m[i][7] = b.w;
        }
        const int tb = tg >> 5;                 // global 32-key block
        const int u  = tblk & 3;                // t-chunk within block
        unsigned short* vb = Vblk + ((size_t)hd * 64 + tb) * 2048;
#pragma unroll
        for (int j = 0; j < 8; ++j) {
            const int d  = dblk * 8 + j;
            const int rv = (d + (d >> 1)) & 3;
            frag8 r;
#pragma unroll
            for (int i = 0; i < 8; ++i) r[i] = (short)f2bf(m[i][j]);
            *(frag8*)(vb + d * 32 + ((u + rv) & 3) * 8) = r;
        }
    }
}

// ---------------- main: R5 verified 32-key pipelined flash ----------------
template <bool MASKED>
__device__ __forceinline__ void
ctile(const unsigned short* __restrict__ Kl, const unsigned short* __restrict__ Vl,
      int t0, int rowBase, int quad, int ln,
      const frag8& aq0, const frag8& aq1,
      unsigned short* __restrict__ PlW, f32x4 acc[4], float l_part[4])
{
    const int sw0 = ((quad + ln) & 7) * 8;       // K chunk swizzle
    const int sw1 = ((quad + 4 + ln) & 7) * 8;
    frag8 bk00 = *(const frag8*)(Kl + ln * 64 + sw0);
    frag8 bk01 = *(const frag8*)(Kl + ln * 64 + sw1);
    frag8 bk10 = *(const frag8*)(Kl + (16 + ln) * 64 + sw0);
    frag8 bk11 = *(const frag8*)(Kl + (16 + ln) * 64 + sw1);

    f32x4 c0 = (f32x4){0.f, 0.f, 0.f, 0.f};
    f32x4 c1 = (f32x4){0.f, 0.f, 0.f, 0.f};
    c0 = __builtin_amdgcn_mfma_f32_16x16x32_bf16(aq0, bk00, c0, 0, 0, 0);
    c0 = __builtin_amdgcn_mfma_f32_16x16x32_bf16(aq1, bk01, c0, 0, 0, 0);
    c1 = __builtin_amdgcn_mfma_f32_16x16x32_bf16(aq0, bk10, c1, 0, 0, 0);
    c1 = __builtin_amdgcn_mfma_f32_16x16x32_bf16(aq1, bk11, c1, 0, 0, 0);

#pragma unroll
    for (int r = 0; r < 4; ++r) {
        float p0 = fexp2(c0[r]);                 // Q pre-scaled -> base-2 domain
        float p1 = fexp2(c1[r]);
        if (MASKED) {
            const int row = rowBase + quad * 4 + r;
            p0 = (t0 + ln > row)      ? 0.f : p0;
            p1 = (t0 + 16 + ln > row) ? 0.f : p1;
        }
        l_part[r] += p0 + p1;
        // round-half-up bf16: 1 VALU + high-half store
        const unsigned u0 = __float_as_uint(p0) + 0x8000u;
        const unsigned u1 = __float_as_uint(p1) + 0x8000u;
        PlW[(quad * 4 + r) * P_P + ln]      = (unsigned short)(u0 >> 16);
        PlW[(quad * 4 + r) * P_P + 16 + ln] = (unsigned short)(u1 >> 16);
    }

    // V frags (independent of P; overlap with P-write latency)
    const int rv  = (ln + (ln >> 1)) & 3;
    const int swv = ((quad + rv) & 3) * 8;
    frag8 bv0 = *(const frag8*)(Vl + (0 * 16 + ln) * 32 + swv);
    frag8 bv1 = *(const frag8*)(Vl + (1 * 16 + ln) * 32 + swv);
    frag8 bv2 = *(const frag8*)(Vl + (2 * 16 + ln) * 32 + swv);
    frag8 bv3 = *(const frag8*)(Vl + (3 * 16 + ln) * 32 + swv);

    asm volatile("s_waitcnt lgkmcnt(0)" ::: "memory");  // P RAW (wave-private)
    frag8 ap = *(const frag8*)&PlW[ln * P_P + quad * 8];
    acc[0] = __builtin_amdgcn_mfma_f32_16x16x32_bf16(ap, bv0, acc[0], 0, 0, 0);
    acc[1] = __builtin_amdgcn_mfma_f32_16x16x32_bf16(ap, bv1, acc[1], 0, 0, 0);
    acc[2] = __builtin_amdgcn_mfma_f32_16x16x32_bf16(ap, bv2, acc[2], 0, 0, 0);
    acc[3] = __builtin_amdgcn_mfma_f32_16x16x32_bf16(ap, bv3, acc[3], 0, 0, 0);
}

__global__ void __launch_bounds__(256, 6)
attn_fwd5(const float* __restrict__ Qg,
          const unsigned short* __restrict__ Kh,
          const unsigned short* __restrict__ Vblk,
          float* __restrict__ Og)
{
    // staging double buffer: [buf][K 4KB | V 4KB]; P per-wave
    __shared__ __align__(16) unsigned short sbuf[2][4096];
    __shared__ __align__(16) unsigned short Pl[4][16 * P_P];

    const int tid  = threadIdx.x;
    const int wave = tid >> 6;
    const int lane = tid & 63;
    const int quad = lane >> 4;
    const int ln   = lane & 15;

    const int hd = blockIdx.x & 63;
    const int qt = 31 - (blockIdx.x >> 6);       // heavy q-tiles first
    const int rowBase = qt * 64 + wave * 16;
    const int t0p  = rowBase & ~31;              // this wave's partial tile
    const int tiles = 2 * qt + 2;

    // persistent Q fragments, pre-scaled
    frag8 aq0, aq1;
    {
        const float* qp = Qg + (size_t)(rowBase + ln) * ROWS_ + hd * HN_ + quad * 8;
        aq0 = pack8s(qp, SC2);
        aq1 = pack8s(qp + 32, SC2);
    }

    f32x4 acc[4];
    float l_part[4];
#pragma unroll
    for (int r = 0; r < 4; ++r) {
        l_part[r] = 0.f;
        acc[r] = (f32x4){0.f, 0.f, 0.f, 0.f};
    }

    const unsigned short* khHead = Kh   + (size_t)hd * (SQ_ * HN_);
    const unsigned short* vbHead = Vblk + (size_t)hd * 64 * 2048;
    unsigned short* PlW = &Pl[wave][0];

    // per-wave staging role: waves 0,1 -> K half; waves 2,3 -> V half
    const int koff = (wave < 2) ? wave * 2048 : (wave - 2) * 2048;   // bytes
    const int doff = (wave < 2) ? koff : 4096 + koff;

    // prologue: stage tile 0
    {
        const char* src = (wave < 2) ? ((const char*)khHead) : ((const char*)vbHead);
        const char* s = src + koff + lane * 16;
        char* d = (char*)&sbuf[0][0] + doff;
        gll(s, d);
        gll(s + 1024, d + 1024);
    }

    for (int t = 0; t < tiles; ++t) {
        // A: every wave finished compute(t-1) -> safe to overwrite buf[(t+1)&1]
        asm volatile("s_barrier" ::: "memory");
        {
            const int tn = (t + 1 < tiles) ? t + 1 : t;
            const char* src = (wave < 2) ? ((const char*)(khHead + (size_t)tn * 2048))
                                         : ((const char*)(vbHead + (size_t)tn * 2048));
            const char* s = src + koff + lane * 16;
            char* d = (char*)&sbuf[(t + 1) & 1][0] + doff;
            gll(s, d);
            gll(s + 1024, d + 1024);
        }
        // wait my tile-t loads (2 newest = tile t+1 stay in flight)
        asm volatile("s_waitcnt vmcnt(2)" ::: "memory");
        // B: everyone's tile-t data is in LDS
        asm volatile("s_barrier" ::: "memory");

        const int t0 = t * 32;
        const unsigned short* Kl = &sbuf[t & 1][0];
        const unsigned short* Vl = &sbuf[t & 1][2048];
        if (t0 < t0p)
            ctile<false>(Kl, Vl, t0, rowBase, quad, ln, aq0, aq1, PlW, acc, l_part);
        else if (t0 == t0p)
            ctile<true>(Kl, Vl, t0, rowBase, quad, ln, aq0, aq1, PlW, acc, l_part);
        // waves with t0 > t0p: fully masked, barrier-only
    }
    asm volatile("s_waitcnt vmcnt(0)" ::: "memory");  // drain stray prefetch

    // epilogue: l-reduction, normalize, store
#pragma unroll
    for (int r = 0; r < 4; ++r) {
        float l = l_part[r];
        l += __shfl_xor(l, 1);
        l += __shfl_xor(l, 2);
        l += __shfl_xor(l, 4);
        l += __shfl_xor(l, 8);
        const float inv = 1.0f / l;
        float* op = Og + (size_t)(rowBase + quad * 4 + r) * ROWS_ + hd * HN_ + ln;
        op[0]  = acc[0][r] * inv;
        op[16] = acc[1][r] * inv;
        op[32] = acc[2][r] * inv;
        op[48] = acc[3][r] * inv;
    }
}

// ---------------- fallback: self-contained (no ws) R3-style kernel ----------------
#define VT_P   40
#define MASK2  (-3.0e4f)
#define MINIT  (-1.0e30f)
__global__ void __launch_bounds__(256)
attn_fwd(const float* __restrict__ Qg, const float* __restrict__ Kg,
         const float* __restrict__ Vg, float* __restrict__ Og)
{
    __shared__ __align__(16) unsigned short Vt[HN_ * VT_P];
    __shared__ __align__(16) unsigned short Pl[4][16 * P_P];
    const int tid  = threadIdx.x;
    const int wave = tid >> 6;
    const int lane = tid & 63;
    const int quad = lane >> 4;
    const int ln   = lane & 15;
    const int hd = blockIdx.x % NH_;
    const int qt = 31 - (blockIdx.x / NH_);
    const int q0 = qt * 64;
    const int rowBase = q0 + wave * 16;
    frag8 aq0, aq1;
    {
        const float* qp = Qg + (size_t)(rowBase + ln) * ROWS_ + hd * HN_ + quad * 8;
        aq0 = pack8s(qp, 1.0f);
        aq1 = pack8s(qp + 32, 1.0f);
    }
    f32x4 acc[4];
    float m_i[4], l_i[4];
#pragma unroll
    for (int r = 0; r < 4; ++r) {
        m_i[r] = MINIT; l_i[r] = 0.f;
        acc[r] = (f32x4){0.f, 0.f, 0.f, 0.f};
    }
    const int tEnd = q0 + 64;
    for (int t0 = 0; t0 < tEnd; t0 += 32) {
        __syncthreads();
        {
            const int t  = tid >> 3;
            const int dc = tid & 7;
            const float* vp = Vg + (size_t)(t0 + t) * ROWS_ + hd * HN_ + dc * 8;
            float4 v0 = *(const float4*)vp;
            float4 v1 = *(const float4*)(vp + 4);
            Vt[(dc * 8 + 0) * VT_P + t] = f2bf(v0.x);
            Vt[(dc * 8 + 1) * VT_P + t] = f2bf(v0.y);
            Vt[(dc * 8 + 2) * VT_P + t] = f2bf(v0.z);
            Vt[(dc * 8 + 3) * VT_P + t] = f2bf(v0.w);
            Vt[(dc * 8 + 4) * VT_P + t] = f2bf(v1.x);
            Vt[(dc * 8 + 5) * VT_P + t] = f2bf(v1.y);
            Vt[(dc * 8 + 6) * VT_P + t] = f2bf(v1.z);
            Vt[(dc * 8 + 7) * VT_P + t] = f2bf(v1.w);
        }
        __syncthreads();
        float s0[4], s1[4];
#pragma unroll
        for (int sub = 0; sub < 2; ++sub) {
            const float* kp = Kg + (size_t)(t0 + sub * 16 + ln) * ROWS_ + hd * HN_ + quad * 8;
            frag8 bk0 = pack8s(kp, 1.0f);
            frag8 bk1 = pack8s(kp + 32, 1.0f);
            f32x4 c = (f32x4){0.f, 0.f, 0.f, 0.f};
            c = __builtin_amdgcn_mfma_f32_16x16x32_bf16(aq0, bk0, c, 0, 0, 0);
            c = __builtin_amdgcn_mfma_f32_16x16x32_bf16(aq1, bk1, c, 0, 0, 0);
            const int col = t0 + sub * 16 + ln;
            float* dst = sub ? s1 : s0;
#pragma unroll
            for (int r = 0; r < 4; ++r) {
                const int row = rowBase + quad * 4 + r;
                dst[r] = (col > row) ? MASK2 : c[r] * SC2;
            }
        }
#pragma unroll
        for (int r = 0; r < 4; ++r) {
            float mx = fmaxf(s0[r], s1[r]);
            mx = fmaxf(mx, __shfl_xor(mx, 1));
            mx = fmaxf(mx, __shfl_xor(mx, 2));
            mx = fmaxf(mx, __shfl_xor(mx, 4));
            mx = fmaxf(mx, __shfl_xor(mx, 8));
            const float mnew  = fmaxf(m_i[r], mx);
            const float alpha = fexp2(m_i[r] - mnew);
            const float p0 = fexp2(s0[r] - mnew);
            const float p1 = fexp2(s1[r] - mnew);
            float rs = p0 + p1;
            rs += __shfl_xor(rs, 1);
            rs += __shfl_xor(rs, 2);
            rs += __shfl_xor(rs, 4);
            rs += __shfl_xor(rs, 8);
            l_i[r] = l_i[r] * alpha + rs;
            m_i[r] = mnew;
#pragma unroll
            for (int dc = 0; dc < 4; ++dc) acc[dc][r] *= alpha;
            Pl[wave][(quad * 4 + r) * P_P + ln]      = f2bf(p0);
            Pl[wave][(quad * 4 + r) * P_P + 16 + ln] = f2bf(p1);
        }
        asm volatile("s_waitcnt lgkmcnt(0)" ::: "memory");
        frag8 ap = *(const frag8*)&Pl[wave][ln * P_P + quad * 8];
#pragma unroll
        for (int dc = 0; dc < 4; ++dc) {
            frag8 bv = *(const frag8*)&Vt[(dc * 16 + ln) * VT_P + quad * 8];
            acc[dc] = __builtin_amdgcn_mfma_f32_16x16x32_bf16(ap, bv, acc[dc], 0, 0, 0);
        }
    }
#pragma unroll
    for (int r = 0; r < 4; ++r) {
        const float inv = 1.0f / l_i[r];
        float* op = Og + (size_t)(rowBase + quad * 4 + r) * ROWS_ + hd * HN_ + ln;
#pragma unroll
        for (int dc = 0; dc < 4; ++dc)
            op[dc * 16] = acc[dc][r] * inv;
    }
}

extern "C" void kernel_launch(void* const* d_in, const int* in_sizes, int n_in,
                              void* d_out, int out_size, void* d_ws, size_t ws_size,
                              hipStream_t stream) {
    const float* Q = (const float*)d_in[0];
    const float* K = (const float*)d_in[1];
    const float* V = (const float*)d_in[2];
    // d_in[3] = attention_mask: deterministically causal; handled analytically.
    float* O = (float*)d_out;

    const size_t HALF = (size_t)SQ_ * ROWS_ * sizeof(unsigned short);  // 16 MiB
    if (ws_size >= 2 * HALF) {
        unsigned short* Kh   = (unsigned short*)d_ws;
        unsigned short* Vblk = (unsigned short*)((char*)d_ws + HALF);
        prep_kv2<<<dim3(NH_ * (SQ_ / 256)), dim3(256), 0, stream>>>(K, V, Kh, Vblk);
        attn_fwd5<<<dim3(2048), dim3(256), 0, stream>>>(Q, Kh, Vblk, O);
    } else {
        attn_fwd<<<dim3(2048), dim3(256), 0, stream>>>(Q, K, V, O);
    }
}